// Round 5
// baseline (345.269 us; speedup 1.0000x reference)
//
#include <hip/hip_runtime.h>
#include <hip/hip_bf16.h>
#include <cstdint>
#include <cstddef>

typedef __hip_bfloat16 bf16;
typedef __attribute__((ext_vector_type(8))) __bf16 bf16x8;
typedef __attribute__((ext_vector_type(4))) float floatx4;

#define GPTR(p) ((const __attribute__((address_space(1))) void*)(p))
#define LPTR(p) ((__attribute__((address_space(3))) void*)(p))

__device__ __forceinline__ floatx4 mfma16(bf16x8 a, bf16x8 b, floatx4 c) {
  return __builtin_amdgcn_mfma_f32_16x16x32_bf16(a, b, c, 0, 0, 0);
}

// Pinned 16B global->register load: inline asm so the allocator can neither
// rematerialize it at the use site (r1 failure) nor sink it (r2 failure).
__device__ __forceinline__ bf16x8 gload16(const bf16* p) {
  bf16x8 r;
  asm volatile("global_load_dwordx4 %0, %1, off"
               : "=v"(r)
               : "v"(p)
               : "memory");
  return r;
}

// ---------------------------------------------------------------------------
// fp32 -> bf16 bulk convert
// ---------------------------------------------------------------------------
__global__ __launch_bounds__(256) void cvt_bf16(const float* __restrict__ in,
                                                bf16* __restrict__ out, int n4) {
  for (int i = blockIdx.x * 256 + threadIdx.x; i < n4; i += gridDim.x * 256) {
    float4 v = ((const float4*)in)[i];
    alignas(8) bf16 t[4] = {__float2bfloat16(v.x), __float2bfloat16(v.y),
                            __float2bfloat16(v.z), __float2bfloat16(v.w)};
    *(uint64_t*)(out + (size_t)i * 4) = *(const uint64_t*)t;
  }
}

// ---------------------------------------------------------------------------
// Fused QKV projection: A[8192,1024](bf16) @ [Wq;Wk;Wv](bf16)^T.
// ---------------------------------------------------------------------------
__global__ __launch_bounds__(256) void gemm_qkv(
    const bf16* __restrict__ A, const bf16* __restrict__ Wq,
    const bf16* __restrict__ Wk, const bf16* __restrict__ Wv,
    bf16* __restrict__ qout, bf16* __restrict__ kout,
    bf16* __restrict__ vTout) {
  __shared__ alignas(16) bf16 As[128 * 32];
  __shared__ alignas(16) bf16 Bs[128 * 32];
  const int tid = threadIdx.x;
  const int lane = tid & 63;
  const int w = tid >> 6;
  const int wr = w >> 1, wc = w & 1;
  const int quad = lane >> 4, c = lane & 15;
  const int m0 = blockIdx.y * 128;
  const int nb = blockIdx.x;

  int mode, nloc;
  const bf16* Wp;
  if (nb < 8) {
    mode = 1; Wp = Wq + (size_t)nb * 128 * 1024; nloc = nb * 128;
  } else if (nb < 10) {
    mode = 2; Wp = Wk + (size_t)(nb - 8) * 128 * 1024; nloc = (nb - 8) * 128;
  } else {
    mode = 3; Wp = Wv + (size_t)(nb - 10) * 128 * 1024; nloc = (nb - 10) * 128;
  }

  const int i0 = tid, i1 = tid + 256;
  const bf16* ga0 = A + (size_t)(m0 + (i0 >> 2)) * 1024 + (i0 & 3) * 8;
  const bf16* ga1 = A + (size_t)(m0 + (i1 >> 2)) * 1024 + (i1 & 3) * 8;
  const bf16* gb0 = Wp + (size_t)(i0 >> 2) * 1024 + (i0 & 3) * 8;
  const bf16* gb1 = Wp + (size_t)(i1 >> 2) * 1024 + (i1 & 3) * 8;

  floatx4 acc[4][4] = {};

  for (int kt = 0; kt < 32; ++kt) {
    if (kt) __syncthreads();
    __builtin_amdgcn_global_load_lds(GPTR(ga0), LPTR(&As[i0 * 8]), 16, 0, 0);
    __builtin_amdgcn_global_load_lds(GPTR(ga1), LPTR(&As[i1 * 8]), 16, 0, 0);
    __builtin_amdgcn_global_load_lds(GPTR(gb0), LPTR(&Bs[i0 * 8]), 16, 0, 0);
    __builtin_amdgcn_global_load_lds(GPTR(gb1), LPTR(&Bs[i1 * 8]), 16, 0, 0);
    ga0 += 32; ga1 += 32; gb0 += 32; gb1 += 32;
    __syncthreads();
    bf16x8 af[4], bfr[4];
#pragma unroll
    for (int i = 0; i < 4; ++i)
      af[i] = *(const bf16x8*)&As[(wr * 64 + i * 16 + c) * 32 + quad * 8];
#pragma unroll
    for (int j = 0; j < 4; ++j)
      bfr[j] = *(const bf16x8*)&Bs[(wc * 64 + j * 16 + c) * 32 + quad * 8];
#pragma unroll
    for (int i = 0; i < 4; ++i)
#pragma unroll
      for (int j = 0; j < 4; ++j)
        acc[i][j] = mfma16(af[i], bfr[j], acc[i][j]);
  }

  if (mode == 3) {  // vT[((b*4+g)*64+d)*1024+t]: 4 consecutive t -> 8B store
#pragma unroll
    for (int i = 0; i < 4; ++i)
#pragma unroll
      for (int j = 0; j < 4; ++j) {
        int m = m0 + wr * 64 + i * 16 + quad * 4;
        int n = nloc + wc * 64 + j * 16 + c;
        int b = m >> 10, t = m & 1023, g = n >> 6, d = n & 63;
        alignas(8) bf16 tmp[4];
#pragma unroll
        for (int r = 0; r < 4; ++r) tmp[r] = __float2bfloat16(acc[i][j][r]);
        *(uint64_t*)(vTout + (((size_t)(b * 4 + g)) * 64 + d) * 1024 + t) =
            *(const uint64_t*)tmp;
      }
    return;
  }

  const float scale = (mode == 1) ? 0.125f : 1.0f;
#pragma unroll
  for (int i = 0; i < 4; ++i)
#pragma unroll
    for (int j = 0; j < 4; ++j)
#pragma unroll
      for (int r = 0; r < 4; ++r) {
        int m = m0 + wr * 64 + i * 16 + quad * 4 + r;
        int n = nloc + wc * 64 + j * 16 + c;
        int b = m >> 10, t = m & 1023;
        bf16 v = __float2bfloat16(acc[i][j][r] * scale);
        if (mode == 1) {
          int h = n >> 6;
          qout[(((size_t)(b * 16 + h)) * 1024 + t) * 64 + (n & 63)] = v;
        } else {
          int g = n >> 6;
          kout[(((size_t)(b * 4 + g)) * 1024 + t) * 64 + (n & 63)] = v;
        }
      }
}

// ---------------------------------------------------------------------------
// O-projection: attn[8192,1024](bf16) @ Wo(bf16)^T -> fp32 d_out.
// ---------------------------------------------------------------------------
__global__ __launch_bounds__(256) void gemm_o(const bf16* __restrict__ A,
                                              const bf16* __restrict__ W,
                                              float* __restrict__ out) {
  __shared__ alignas(16) bf16 As[128 * 32];
  __shared__ alignas(16) bf16 Bs[128 * 32];
  const int tid = threadIdx.x;
  const int lane = tid & 63;
  const int w = tid >> 6;
  const int wr = w >> 1, wc = w & 1;
  const int quad = lane >> 4, c = lane & 15;
  const int m0 = blockIdx.y * 128, n0 = blockIdx.x * 128;

  const int i0 = tid, i1 = tid + 256;
  const bf16* ga0 = A + (size_t)(m0 + (i0 >> 2)) * 1024 + (i0 & 3) * 8;
  const bf16* ga1 = A + (size_t)(m0 + (i1 >> 2)) * 1024 + (i1 & 3) * 8;
  const bf16* gb0 = W + (size_t)(n0 + (i0 >> 2)) * 1024 + (i0 & 3) * 8;
  const bf16* gb1 = W + (size_t)(n0 + (i1 >> 2)) * 1024 + (i1 & 3) * 8;

  floatx4 acc[4][4] = {};

  for (int kt = 0; kt < 32; ++kt) {
    if (kt) __syncthreads();
    __builtin_amdgcn_global_load_lds(GPTR(ga0), LPTR(&As[i0 * 8]), 16, 0, 0);
    __builtin_amdgcn_global_load_lds(GPTR(ga1), LPTR(&As[i1 * 8]), 16, 0, 0);
    __builtin_amdgcn_global_load_lds(GPTR(gb0), LPTR(&Bs[i0 * 8]), 16, 0, 0);
    __builtin_amdgcn_global_load_lds(GPTR(gb1), LPTR(&Bs[i1 * 8]), 16, 0, 0);
    ga0 += 32; ga1 += 32; gb0 += 32; gb1 += 32;
    __syncthreads();
    bf16x8 af[4], bfr[4];
#pragma unroll
    for (int i = 0; i < 4; ++i)
      af[i] = *(const bf16x8*)&As[(wr * 64 + i * 16 + c) * 32 + quad * 8];
#pragma unroll
    for (int j = 0; j < 4; ++j)
      bfr[j] = *(const bf16x8*)&Bs[(wc * 64 + j * 16 + c) * 32 + quad * 8];
#pragma unroll
    for (int i = 0; i < 4; ++i)
#pragma unroll
      for (int j = 0; j < 4; ++j)
        acc[i][j] = mfma16(af[i], bfr[j], acc[i][j]);
  }

#pragma unroll
  for (int i = 0; i < 4; ++i)
#pragma unroll
    for (int j = 0; j < 4; ++j)
#pragma unroll
      for (int r = 0; r < 4; ++r) {
        int m = m0 + wr * 64 + i * 16 + quad * 4 + r;
        int n = n0 + wc * 64 + j * 16 + c;
        out[(size_t)m * 1024 + n] = acc[i][j][r];
      }
}

// ---------------------------------------------------------------------------
// Staged 64x64 bf16 tile with XOR-8 column-block swizzle (verified r0).
// ---------------------------------------------------------------------------
__device__ __forceinline__ void stage_tile_swz(const bf16* __restrict__ g,
                                               int gstride, bf16* __restrict__ dst,
                                               int tid) {
#pragma unroll
  for (int s = 0; s < 2; ++s) {
    int f = s * 256 + tid;
    int r = f >> 3, cb = f & 7;
    int cbg = cb ^ (r & 7);
    __builtin_amdgcn_global_load_lds(GPTR(g + (size_t)r * gstride + cbg * 8),
                                     LPTR(dst + f * 8), 16, 0, 0);
  }
}

__device__ __forceinline__ bf16x8 read_frag_swz(const bf16* __restrict__ tile,
                                                int row, int cb) {
  return *(const bf16x8*)&tile[row * 64 + ((cb ^ (row & 7)) * 8)];
}

// ---------------------------------------------------------------------------
// Flash attention, S^T = K.Q^T form.  Round-5.
// r4 post-mortem: pipeline worked but LDS 68.6KB dropped occupancy to
// 2 blocks/CU; net wash.  Invariant across r0-r4: VALUBusy~37%, ~50% of
// cycles idle -> serial softmax chain (ds_bpermute shuffles, alpha bcast,
// o-rescale, exp) is the floor; occupancy is the multiplier.  This round:
//   1. T13 defer-rescale THR=8: skip {max-reduce shuffles, alpha exp,
//      4 alpha-bcast shuffles, 16 o-muls} unless some row max grew >8
//      (ballot on lane-local max; ~2-3 of 16 tiles trigger).  P<=e^8 in
//      bf16 keeps identical relative precision (HW-verified technique).
//   2. l kept as per-lane PARTIAL (each lane covers one quad's kv slice;
//      alpha is row-uniform so partial update is exact) -> the 2 rs
//      shuffles per tile move to a single end-of-kernel reduction.
//   3. V direct->register via pinned asm global_load_dwordx4 issued at
//      tile top BEFORE the K prefetch; s_waitcnt vmcnt(2) before PV waits
//      on REGISTER loads only (precise semantics; the r3 race was LDS-write
//      visibility of global_load_lds, which here only ever sees vmcnt(0)).
//      sched_barrier(0) after the wait per rule #18.  V leaves LDS:
//      52224 B -> 3 blocks/CU restored, K double-buffer pipeline kept.
//   4. T5 setprio(1) around both MFMA clusters.
// ---------------------------------------------------------------------------
__device__ __forceinline__ void attn_tile(
    int t0, const bf16* __restrict__ kbase, const bf16* __restrict__ vbase,
    bf16* __restrict__ curK, bf16* __restrict__ nxtK,
    const bf16* __restrict__ rowE, int qb, int tid, int w, int quad, int c,
    bf16x8 qf0, bf16x8 qf1, float blo, float bhi, float& mrow, float& lpart,
    floatx4 (&o)[4]) {
  // --- V tile -> registers (8 pinned asm loads; oldest vmem this tile)
  bf16x8 vf[4][2];
#pragma unroll
  for (int jj = 0; jj < 4; ++jj) {
    const bf16* vr = vbase + (size_t)(jj * 16 + c) * 1024 + t0 + quad * 8;
    vf[jj][0] = gload16(vr);
    vf[jj][1] = gload16(vr + 32);
  }
  // --- prefetch NEXT K tile (2 global_load_lds, youngest; drained at END)
  const int nt0 = (t0 + 64) & 1023;
  stage_tile_swz(kbase + (size_t)nt0 * 64, 64, nxtK, tid);
  // --- QK^T from curK (landed + barrier'd at end of previous tile)
  floatx4 S[4];
  __builtin_amdgcn_s_setprio(1);
#pragma unroll
  for (int j = 0; j < 4; ++j) {
    bf16x8 kf0 = read_frag_swz(curK, j * 16 + c, quad);
    bf16x8 kf1 = read_frag_swz(curK, j * 16 + c, quad + 4);
    floatx4 z = {};
    z = mfma16(kf0, qf0, z);
    S[j] = mfma16(kf1, qf1, z);
  }
  __builtin_amdgcn_s_setprio(0);
  // --- relative-position bias (branch is wave-uniform: qb,t0)
  const int dlt0 = qb + c - t0;
  if (t0 <= qb - 190) {
#pragma unroll
    for (int j = 0; j < 4; ++j)
#pragma unroll
      for (int r = 0; r < 4; ++r) S[j][r] += blo;
  } else if (t0 >= qb + 142) {
#pragma unroll
    for (int j = 0; j < 4; ++j)
#pragma unroll
      for (int r = 0; r < 4; ++r) S[j][r] += bhi;
  } else {
#pragma unroll
    for (int j = 0; j < 4; ++j)
#pragma unroll
      for (int r = 0; r < 4; ++r) {
        int dlt = dlt0 - j * 16 - quad * 4 - r;
        dlt = dlt > 127 ? 127 : (dlt < -127 ? -127 : dlt);
        S[j][r] += __bfloat162float(rowE[dlt + 127]);
      }
  }
  // --- T13 defer-rescale online softmax
  float mx = S[0][0];
#pragma unroll
  for (int j = 0; j < 4; ++j)
#pragma unroll
    for (int r = 0; r < 4; ++r) mx = fmaxf(mx, S[j][r]);
  if (__ballot(mx > mrow + 8.f)) {
    // some row's max grew: full cross-lane reduce + rescale (rare path)
    float fm = fmaxf(mx, __shfl_xor(mx, 16, 64));
    fm = fmaxf(fm, __shfl_xor(fm, 32, 64));
    float nm = fmaxf(mrow, fm);
    float alpha = __expf(mrow - nm);
    float av[4];
#pragma unroll
    for (int r = 0; r < 4; ++r) av[r] = __shfl(alpha, quad * 4 + r, 64);
#pragma unroll
    for (int jj = 0; jj < 4; ++jj)
#pragma unroll
      for (int r = 0; r < 4; ++r) o[jj][r] *= av[r];
    lpart *= alpha;
    mrow = nm;
  }
  float rs = 0.f;
#pragma unroll
  for (int j = 0; j < 4; ++j)
#pragma unroll
    for (int r = 0; r < 4; ++r) {
      float p = __expf(S[j][r] - mrow);  // bounded by e^8
      S[j][r] = p;
      rs += p;
    }
  lpart += rs;  // per-lane partial (quad's kv slice); reduced once at end
  // --- mid barrier: all waves arrived => all curK ds_reads complete.
  __builtin_amdgcn_sched_barrier(0);
  __builtin_amdgcn_s_barrier();
  __builtin_amdgcn_sched_barrier(0);
  // --- P through wave-private stride-72 rows aliased on curK
  bf16* rowP = curK + (size_t)(w * 16 + c) * 72;
#pragma unroll
  for (int j = 0; j < 4; ++j) {
    alignas(8) bf16 tmp[4];
#pragma unroll
    for (int r = 0; r < 4; ++r) tmp[r] = __float2bfloat16(S[j][r]);
    *(uint64_t*)(rowP + j * 16 + quad * 4) = *(const uint64_t*)tmp;
  }
  __threadfence_block();
  __builtin_amdgcn_wave_barrier();
  bf16x8 pf0 = *(const bf16x8*)(rowP + quad * 8);
  bf16x8 pf1 = *(const bf16x8*)(rowP + 32 + quad * 8);
  // --- V register loads complete (only the 2 K gload_lds remain in flight)
  asm volatile("s_waitcnt vmcnt(2)" ::: "memory");
  __builtin_amdgcn_sched_barrier(0);
  __builtin_amdgcn_s_setprio(1);
#pragma unroll
  for (int jj = 0; jj < 4; ++jj) {
    o[jj] = mfma16(pf0, vf[jj][0], o[jj]);
    o[jj] = mfma16(pf1, vf[jj][1], o[jj]);
  }
  __builtin_amdgcn_s_setprio(0);
  // --- end: K[t+1] LDS writes landed; all waves done with P -> restage ok.
  asm volatile("s_waitcnt vmcnt(0)" ::: "memory");
  __builtin_amdgcn_sched_barrier(0);
  __builtin_amdgcn_s_barrier();
  __builtin_amdgcn_sched_barrier(0);
}

__global__ __launch_bounds__(256, 3) void attn_kernel(
    const bf16* __restrict__ q_ws, const bf16* __restrict__ k_ws,
    const bf16* __restrict__ vT, const float* __restrict__ E,
    bf16* __restrict__ out) {
  __shared__ alignas(16) bf16 qEl[64 * 264];  // bias table, rows lane-private
  __shared__ alignas(16) bf16 Ka[64 * 72];    // K buf A / P rows
  __shared__ alignas(16) bf16 Kc[64 * 72];    // K buf B / P rows
  const int tid = threadIdx.x;
  const int lane = tid & 63, w = tid >> 6;
  const int quad = lane >> 4, c = lane & 15;
  const int bh = blockIdx.y;
  const int b = bh >> 4, h = bh & 15, g = h >> 2;
  const int qb = blockIdx.x * 64 + w * 16;

  const bf16* kbase = k_ws + (size_t)(b * 4 + g) * 1024 * 64;
  const bf16* vbase = vT + (size_t)(b * 4 + g) * 64 * 1024;

  // K tile 0 prefetch hides under the qE preamble; the preamble's
  // __syncthreads (full drain) lands it for all waves.
  stage_tile_swz(kbase, 64, Ka, tid);

  const bf16* qrow = q_ws + ((size_t)bh * 1024 + qb + c) * 64;
  bf16x8 qf0 = *(const bf16x8*)(qrow + quad * 8);
  bf16x8 qf1 = *(const bf16x8*)(qrow + 32 + quad * 8);

  // qE[qlocal][p] = q.E[p]  (wave's rows w*16..w*16+15; p in [0,254])
  for (int jn = 0; jn < 16; ++jn) {
    int er = jn * 16 + c;
    er = er > 254 ? 254 : er;
    const float* Ep = E + (size_t)er * 64;
    float4 e0 = *(const float4*)(Ep + quad * 8);
    float4 e1 = *(const float4*)(Ep + quad * 8 + 4);
    float4 e2 = *(const float4*)(Ep + 32 + quad * 8);
    float4 e3 = *(const float4*)(Ep + 32 + quad * 8 + 4);
    alignas(16) bf16 t0b[8] = {
        __float2bfloat16(e0.x), __float2bfloat16(e0.y), __float2bfloat16(e0.z),
        __float2bfloat16(e0.w), __float2bfloat16(e1.x), __float2bfloat16(e1.y),
        __float2bfloat16(e1.z), __float2bfloat16(e1.w)};
    alignas(16) bf16 t1b[8] = {
        __float2bfloat16(e2.x), __float2bfloat16(e2.y), __float2bfloat16(e2.z),
        __float2bfloat16(e2.w), __float2bfloat16(e3.x), __float2bfloat16(e3.y),
        __float2bfloat16(e3.z), __float2bfloat16(e3.w)};
    floatx4 a = {};
    a = mfma16(qf0, *(const bf16x8*)t0b, a);
    a = mfma16(qf1, *(const bf16x8*)t1b, a);
#pragma unroll
    for (int r = 0; r < 4; ++r)
      qEl[(w * 16 + quad * 4 + r) * 264 + jn * 16 + c] = __float2bfloat16(a[r]);
  }
  __syncthreads();  // qEl ready + K0 landed (single full drain)

  const bf16* rowE = qEl + (size_t)(w * 16 + c) * 264;
  float mrow = -1e30f, lpart = 0.f;
  floatx4 o[4] = {};
  const float blo = __bfloat162float(rowE[254]);
  const float bhi = __bfloat162float(rowE[0]);

  // 16 tiles, unrolled x2 so the K buffer choice is compile-time static.
#pragma unroll 1
  for (int tp = 0; tp < 8; ++tp) {
    attn_tile(tp * 128, kbase, vbase, Ka, Kc, rowE, qb, tid, w, quad, c,
              qf0, qf1, blo, bhi, mrow, lpart, o);
    attn_tile(tp * 128 + 64, kbase, vbase, Kc, Ka, rowE, qb, tid, w, quad, c,
              qf0, qf1, blo, bhi, mrow, lpart, o);
  }

  // one-time l reduction: per-lane partials -> row totals
  float lsum = lpart + __shfl_xor(lpart, 16, 64);
  lsum += __shfl_xor(lsum, 32, 64);
  float lr4[4];
#pragma unroll
  for (int r = 0; r < 4; ++r) lr4[r] = __shfl(lsum, quad * 4 + r, 64);
#pragma unroll
  for (int jj = 0; jj < 4; ++jj)
#pragma unroll
    for (int r = 0; r < 4; ++r) {
      int qi = qb + quad * 4 + r;
      out[(((size_t)b * 1024 + qi) * 16 + h) * 64 + jj * 16 + c] =
          __float2bfloat16(o[jj][r] / lr4[r]);
    }
}

// ---------------------------------------------------------------------------
// Memory plan (unchanged, proven):
//   d_out (32 MB fp32): [0,16M) q bf16 | [16M,32M) x_bf16.
//   ws: k 4MB @0 | vT 4MB @4M | attn 16MB @8M
//   Wq/Wk/Wv_bf @8M/10M/10.5M (attn region, dead before attn_kernel writes).
//   Wo_bf @0 (k region; converted AFTER attn_kernel consumed k).
// ---------------------------------------------------------------------------
extern "C" void kernel_launch(void* const* d_in, const int* in_sizes, int n_in,
                              void* d_out, int out_size, void* d_ws,
                              size_t ws_size, hipStream_t stream) {
  const float* x = (const float*)d_in[0];
  const float* Wq = (const float*)d_in[1];
  const float* Wk = (const float*)d_in[2];
  const float* Wv = (const float*)d_in[3];
  const float* Wo = (const float*)d_in[4];
  const float* E = (const float*)d_in[5];

  char* ws = (char*)d_ws;
  bf16* q_ws = (bf16*)d_out;                           // [0,16M) of d_out
  bf16* x_bf = (bf16*)((char*)d_out + (16ull << 20));  // [16M,32M) of d_out
  bf16* k_ws = (bf16*)(ws);
  bf16* vT = (bf16*)(ws + (4ull << 20));
  bf16* attn = (bf16*)(ws + (8ull << 20));
  bf16* Wq_bf = (bf16*)(ws + (8ull << 20));            // 2 MB   (attn region)
  bf16* Wk_bf = (bf16*)(ws + (10ull << 20));           // 0.5 MB (attn region)
  bf16* Wv_bf = (bf16*)(ws + (10ull << 20) + (512ull << 10));  // 0.5 MB
  bf16* Wo_bf = (bf16*)(ws);                           // 2 MB   (k region)
  float* outp = (float*)d_out;

  cvt_bf16<<<2048, 256, 0, stream>>>(x, x_bf, 2097152);
  cvt_bf16<<<1024, 256, 0, stream>>>(Wq, Wq_bf, 262144);
  cvt_bf16<<<256, 256, 0, stream>>>(Wk, Wk_bf, 65536);
  cvt_bf16<<<256, 256, 0, stream>>>(Wv, Wv_bf, 65536);
  gemm_qkv<<<dim3(12, 64), 256, 0, stream>>>(x_bf, Wq_bf, Wk_bf, Wv_bf,
                                             q_ws, k_ws, vT);
  attn_kernel<<<dim3(16, 128), 256, 0, stream>>>(q_ws, k_ws, vT, E, attn);
  cvt_bf16<<<1024, 256, 0, stream>>>(Wo, Wo_bf, 262144);
  gemm_o<<<dim3(8, 64), 256, 0, stream>>>(attn, Wo_bf, outp);
}

// Round 6
// 278.660 us; speedup vs baseline: 1.2390x; 1.2390x over previous
//
#include <hip/hip_runtime.h>
#include <hip/hip_bf16.h>
#include <cstdint>
#include <cstddef>

typedef __hip_bfloat16 bf16;
typedef __attribute__((ext_vector_type(8))) __bf16 bf16x8;
typedef __attribute__((ext_vector_type(4))) float floatx4;

#define GPTR(p) ((const __attribute__((address_space(1))) void*)(p))
#define LPTR(p) ((__attribute__((address_space(3))) void*)(p))

__device__ __forceinline__ floatx4 mfma16(bf16x8 a, bf16x8 b, floatx4 c) {
  return __builtin_amdgcn_mfma_f32_16x16x32_bf16(a, b, c, 0, 0, 0);
}

// ---------------------------------------------------------------------------
// fp32 -> bf16 bulk convert
// ---------------------------------------------------------------------------
__global__ __launch_bounds__(256) void cvt_bf16(const float* __restrict__ in,
                                                bf16* __restrict__ out, int n4) {
  for (int i = blockIdx.x * 256 + threadIdx.x; i < n4; i += gridDim.x * 256) {
    float4 v = ((const float4*)in)[i];
    alignas(8) bf16 t[4] = {__float2bfloat16(v.x), __float2bfloat16(v.y),
                            __float2bfloat16(v.z), __float2bfloat16(v.w)};
    *(uint64_t*)(out + (size_t)i * 4) = *(const uint64_t*)t;
  }
}

// ---------------------------------------------------------------------------
// Fused QKV projection: A[8192,1024](bf16) @ [Wq;Wk;Wv](bf16)^T.
// m97 structure: 128x128 tile, BK=32, both sides global_load_lds width=16.
// ---------------------------------------------------------------------------
__global__ __launch_bounds__(256) void gemm_qkv(
    const bf16* __restrict__ A, const bf16* __restrict__ Wq,
    const bf16* __restrict__ Wk, const bf16* __restrict__ Wv,
    bf16* __restrict__ qout, bf16* __restrict__ kout,
    bf16* __restrict__ vTout) {
  __shared__ alignas(16) bf16 As[128 * 32];
  __shared__ alignas(16) bf16 Bs[128 * 32];
  const int tid = threadIdx.x;
  const int lane = tid & 63;
  const int w = tid >> 6;
  const int wr = w >> 1, wc = w & 1;
  const int quad = lane >> 4, c = lane & 15;
  const int m0 = blockIdx.y * 128;
  const int nb = blockIdx.x;

  int mode, nloc;
  const bf16* Wp;
  if (nb < 8) {
    mode = 1; Wp = Wq + (size_t)nb * 128 * 1024; nloc = nb * 128;
  } else if (nb < 10) {
    mode = 2; Wp = Wk + (size_t)(nb - 8) * 128 * 1024; nloc = (nb - 8) * 128;
  } else {
    mode = 3; Wp = Wv + (size_t)(nb - 10) * 128 * 1024; nloc = (nb - 10) * 128;
  }

  const int i0 = tid, i1 = tid + 256;
  const bf16* ga0 = A + (size_t)(m0 + (i0 >> 2)) * 1024 + (i0 & 3) * 8;
  const bf16* ga1 = A + (size_t)(m0 + (i1 >> 2)) * 1024 + (i1 & 3) * 8;
  const bf16* gb0 = Wp + (size_t)(i0 >> 2) * 1024 + (i0 & 3) * 8;
  const bf16* gb1 = Wp + (size_t)(i1 >> 2) * 1024 + (i1 & 3) * 8;

  floatx4 acc[4][4] = {};

  for (int kt = 0; kt < 32; ++kt) {
    if (kt) __syncthreads();
    __builtin_amdgcn_global_load_lds(GPTR(ga0), LPTR(&As[i0 * 8]), 16, 0, 0);
    __builtin_amdgcn_global_load_lds(GPTR(ga1), LPTR(&As[i1 * 8]), 16, 0, 0);
    __builtin_amdgcn_global_load_lds(GPTR(gb0), LPTR(&Bs[i0 * 8]), 16, 0, 0);
    __builtin_amdgcn_global_load_lds(GPTR(gb1), LPTR(&Bs[i1 * 8]), 16, 0, 0);
    ga0 += 32; ga1 += 32; gb0 += 32; gb1 += 32;
    __syncthreads();
    bf16x8 af[4], bfr[4];
#pragma unroll
    for (int i = 0; i < 4; ++i)
      af[i] = *(const bf16x8*)&As[(wr * 64 + i * 16 + c) * 32 + quad * 8];
#pragma unroll
    for (int j = 0; j < 4; ++j)
      bfr[j] = *(const bf16x8*)&Bs[(wc * 64 + j * 16 + c) * 32 + quad * 8];
#pragma unroll
    for (int i = 0; i < 4; ++i)
#pragma unroll
      for (int j = 0; j < 4; ++j)
        acc[i][j] = mfma16(af[i], bfr[j], acc[i][j]);
  }

  if (mode == 3) {  // vT[((b*4+g)*64+d)*1024+t]: 4 consecutive t -> 8B store
#pragma unroll
    for (int i = 0; i < 4; ++i)
#pragma unroll
      for (int j = 0; j < 4; ++j) {
        int m = m0 + wr * 64 + i * 16 + quad * 4;
        int n = nloc + wc * 64 + j * 16 + c;
        int b = m >> 10, t = m & 1023, g = n >> 6, d = n & 63;
        alignas(8) bf16 tmp[4];
#pragma unroll
        for (int r = 0; r < 4; ++r) tmp[r] = __float2bfloat16(acc[i][j][r]);
        *(uint64_t*)(vTout + (((size_t)(b * 4 + g)) * 64 + d) * 1024 + t) =
            *(const uint64_t*)tmp;
      }
    return;
  }

  const float scale = (mode == 1) ? 0.125f : 1.0f;
#pragma unroll
  for (int i = 0; i < 4; ++i)
#pragma unroll
    for (int j = 0; j < 4; ++j)
#pragma unroll
      for (int r = 0; r < 4; ++r) {
        int m = m0 + wr * 64 + i * 16 + quad * 4 + r;
        int n = nloc + wc * 64 + j * 16 + c;
        int b = m >> 10, t = m & 1023;
        bf16 v = __float2bfloat16(acc[i][j][r] * scale);
        if (mode == 1) {
          int h = n >> 6;
          qout[(((size_t)(b * 16 + h)) * 1024 + t) * 64 + (n & 63)] = v;
        } else {
          int g = n >> 6;
          kout[(((size_t)(b * 4 + g)) * 1024 + t) * 64 + (n & 63)] = v;
        }
      }
}

// ---------------------------------------------------------------------------
// O-projection: attn[8192,1024](bf16) @ Wo(bf16)^T -> fp32 d_out.
// ---------------------------------------------------------------------------
__global__ __launch_bounds__(256) void gemm_o(const bf16* __restrict__ A,
                                              const bf16* __restrict__ W,
                                              float* __restrict__ out) {
  __shared__ alignas(16) bf16 As[128 * 32];
  __shared__ alignas(16) bf16 Bs[128 * 32];
  const int tid = threadIdx.x;
  const int lane = tid & 63;
  const int w = tid >> 6;
  const int wr = w >> 1, wc = w & 1;
  const int quad = lane >> 4, c = lane & 15;
  const int m0 = blockIdx.y * 128, n0 = blockIdx.x * 128;

  const int i0 = tid, i1 = tid + 256;
  const bf16* ga0 = A + (size_t)(m0 + (i0 >> 2)) * 1024 + (i0 & 3) * 8;
  const bf16* ga1 = A + (size_t)(m0 + (i1 >> 2)) * 1024 + (i1 & 3) * 8;
  const bf16* gb0 = W + (size_t)(n0 + (i0 >> 2)) * 1024 + (i0 & 3) * 8;
  const bf16* gb1 = W + (size_t)(n0 + (i1 >> 2)) * 1024 + (i1 & 3) * 8;

  floatx4 acc[4][4] = {};

  for (int kt = 0; kt < 32; ++kt) {
    if (kt) __syncthreads();
    __builtin_amdgcn_global_load_lds(GPTR(ga0), LPTR(&As[i0 * 8]), 16, 0, 0);
    __builtin_amdgcn_global_load_lds(GPTR(ga1), LPTR(&As[i1 * 8]), 16, 0, 0);
    __builtin_amdgcn_global_load_lds(GPTR(gb0), LPTR(&Bs[i0 * 8]), 16, 0, 0);
    __builtin_amdgcn_global_load_lds(GPTR(gb1), LPTR(&Bs[i1 * 8]), 16, 0, 0);
    ga0 += 32; ga1 += 32; gb0 += 32; gb1 += 32;
    __syncthreads();
    bf16x8 af[4], bfr[4];
#pragma unroll
    for (int i = 0; i < 4; ++i)
      af[i] = *(const bf16x8*)&As[(wr * 64 + i * 16 + c) * 32 + quad * 8];
#pragma unroll
    for (int j = 0; j < 4; ++j)
      bfr[j] = *(const bf16x8*)&Bs[(wc * 64 + j * 16 + c) * 32 + quad * 8];
#pragma unroll
    for (int i = 0; i < 4; ++i)
#pragma unroll
      for (int j = 0; j < 4; ++j)
        acc[i][j] = mfma16(af[i], bfr[j], acc[i][j]);
  }

#pragma unroll
  for (int i = 0; i < 4; ++i)
#pragma unroll
    for (int j = 0; j < 4; ++j)
#pragma unroll
      for (int r = 0; r < 4; ++r) {
        int m = m0 + wr * 64 + i * 16 + quad * 4 + r;
        int n = n0 + wc * 64 + j * 16 + c;
        out[(size_t)m * 1024 + n] = acc[i][j][r];
      }
}

// ---------------------------------------------------------------------------
// Staged 64x64 bf16 tile with XOR-8 column-block swizzle (verified r0).
// ---------------------------------------------------------------------------
__device__ __forceinline__ void stage_tile_swz(const bf16* __restrict__ g,
                                               int gstride, bf16* __restrict__ dst,
                                               int tid) {
#pragma unroll
  for (int s = 0; s < 2; ++s) {
    int f = s * 256 + tid;
    int r = f >> 3, cb = f & 7;
    int cbg = cb ^ (r & 7);
    __builtin_amdgcn_global_load_lds(GPTR(g + (size_t)r * gstride + cbg * 8),
                                     LPTR(dst + f * 8), 16, 0, 0);
  }
}

__device__ __forceinline__ bf16x8 read_frag_swz(const bf16* __restrict__ tile,
                                                int row, int cb) {
  return *(const bf16x8*)&tile[row * 64 + ((cb ^ (row & 7)) * 8)];
}

// ---------------------------------------------------------------------------
// Flash attention, S^T = K.Q^T form.  Round-6.
// r5 post-mortem: per-wave V register loads = each wave loads the WHOLE
// 8KB V tile (fragments are lane-distributed) -> 4x V traffic per block,
// TA/L1-bound, 196us.  Shared tiles must be staged once per block.
// This round: EXACT r0 structure (135us, 3 blocks/CU, K+V LDS-staged,
// 3 barriers/tile) with ONLY the softmax diet validated in r5:
//   1. T13 defer-rescale THR=8: common path (~15/16 tiles) skips the
//      2 max-reduce shuffles, alpha exp, 4 alpha-bcast shuffles,
//      16 o-muls -- all on the serial chain before the mid-barrier.
//   2. l as per-lane partial (alpha row-uniform across quads -> exact);
//      2 more shuffles/tile deleted; single 2-shuffle reduce at end.
// Single-variable A/B vs the 135.3us r0 baseline.
// LDS: qEl 33792 + K/P 9216 + V 8192 = 51200 -> 3 blocks/CU.
// ---------------------------------------------------------------------------
__global__ __launch_bounds__(256, 3) void attn_kernel(
    const bf16* __restrict__ q_ws, const bf16* __restrict__ k_ws,
    const bf16* __restrict__ vT, const float* __restrict__ E,
    bf16* __restrict__ out) {
  __shared__ alignas(16) bf16 qEl[64 * 264];  // bias table, rows lane-private
  __shared__ alignas(16) bf16 Ks[64 * 72];    // K tile (staged 64x64) / P rows
  __shared__ alignas(16) bf16 Vs[64 * 64];    // V^T tile
  const int tid = threadIdx.x;
  const int lane = tid & 63, w = tid >> 6;
  const int quad = lane >> 4, c = lane & 15;
  const int bh = blockIdx.y;
  const int b = bh >> 4, h = bh & 15, g = h >> 2;
  const int qb = blockIdx.x * 64 + w * 16;

  const bf16* qrow = q_ws + ((size_t)bh * 1024 + qb + c) * 64;
  bf16x8 qf0 = *(const bf16x8*)(qrow + quad * 8);
  bf16x8 qf1 = *(const bf16x8*)(qrow + 32 + quad * 8);

  // qE[qlocal][p] = q.E[p]  (wave's rows w*16..w*16+15; p in [0,254])
  for (int jn = 0; jn < 16; ++jn) {
    int er = jn * 16 + c;
    er = er > 254 ? 254 : er;
    const float* Ep = E + (size_t)er * 64;
    float4 e0 = *(const float4*)(Ep + quad * 8);
    float4 e1 = *(const float4*)(Ep + quad * 8 + 4);
    float4 e2 = *(const float4*)(Ep + 32 + quad * 8);
    float4 e3 = *(const float4*)(Ep + 32 + quad * 8 + 4);
    alignas(16) bf16 t0b[8] = {
        __float2bfloat16(e0.x), __float2bfloat16(e0.y), __float2bfloat16(e0.z),
        __float2bfloat16(e0.w), __float2bfloat16(e1.x), __float2bfloat16(e1.y),
        __float2bfloat16(e1.z), __float2bfloat16(e1.w)};
    alignas(16) bf16 t1b[8] = {
        __float2bfloat16(e2.x), __float2bfloat16(e2.y), __float2bfloat16(e2.z),
        __float2bfloat16(e2.w), __float2bfloat16(e3.x), __float2bfloat16(e3.y),
        __float2bfloat16(e3.z), __float2bfloat16(e3.w)};
    floatx4 a = {};
    a = mfma16(qf0, *(const bf16x8*)t0b, a);
    a = mfma16(qf1, *(const bf16x8*)t1b, a);
#pragma unroll
    for (int r = 0; r < 4; ++r)
      qEl[(w * 16 + quad * 4 + r) * 264 + jn * 16 + c] = __float2bfloat16(a[r]);
  }
  __syncthreads();  // qEl ready for all waves

  const bf16* rowE = qEl + (size_t)(w * 16 + c) * 264;
  bf16* rowP = Ks + (size_t)(w * 16 + c) * 72;
  float mrow = -1e30f, lpart = 0.f;
  floatx4 o[4] = {};
  const bf16* kbase = k_ws + (size_t)(b * 4 + g) * 1024 * 64;
  const bf16* vbase = vT + (size_t)(b * 4 + g) * 64 * 1024;
  const float blo = __bfloat162float(rowE[254]);
  const float bhi = __bfloat162float(rowE[0]);

  for (int t0 = 0; t0 < 1024; t0 += 64) {
    stage_tile_swz(kbase + (size_t)t0 * 64, 64, Ks, tid);
    stage_tile_swz(vbase + t0, 1024, Vs, tid);
    __syncthreads();  // A: staging landed
    floatx4 S[4];
#pragma unroll
    for (int j = 0; j < 4; ++j) {
      bf16x8 kf0 = read_frag_swz(Ks, j * 16 + c, quad);
      bf16x8 kf1 = read_frag_swz(Ks, j * 16 + c, quad + 4);
      floatx4 z = {};
      z = mfma16(kf0, qf0, z);
      S[j] = mfma16(kf1, qf1, z);
    }
    const int dlt0 = qb + c - t0;
    if (t0 <= qb - 190) {
#pragma unroll
      for (int j = 0; j < 4; ++j)
#pragma unroll
        for (int r = 0; r < 4; ++r) S[j][r] += blo;
    } else if (t0 >= qb + 142) {
#pragma unroll
      for (int j = 0; j < 4; ++j)
#pragma unroll
        for (int r = 0; r < 4; ++r) S[j][r] += bhi;
    } else {
#pragma unroll
      for (int j = 0; j < 4; ++j)
#pragma unroll
        for (int r = 0; r < 4; ++r) {
          int dlt = dlt0 - j * 16 - quad * 4 - r;
          dlt = dlt > 127 ? 127 : (dlt < -127 ? -127 : dlt);
          S[j][r] += __bfloat162float(rowE[dlt + 127]);
        }
    }
    // --- T13 defer-rescale online softmax
    float mx = S[0][0];
#pragma unroll
    for (int j = 0; j < 4; ++j)
#pragma unroll
      for (int r = 0; r < 4; ++r) mx = fmaxf(mx, S[j][r]);
    if (__ballot(mx > mrow + 8.f)) {
      // rare path (tile 0 + genuine max growth): full reduce + rescale
      float fm = fmaxf(mx, __shfl_xor(mx, 16, 64));
      fm = fmaxf(fm, __shfl_xor(fm, 32, 64));
      float nm = fmaxf(mrow, fm);
      float alpha = __expf(mrow - nm);
      float av[4];
#pragma unroll
      for (int r = 0; r < 4; ++r) av[r] = __shfl(alpha, quad * 4 + r, 64);
#pragma unroll
      for (int jj = 0; jj < 4; ++jj)
#pragma unroll
        for (int r = 0; r < 4; ++r) o[jj][r] *= av[r];
      lpart *= alpha;
      mrow = nm;
    }
    float rs = 0.f;
#pragma unroll
    for (int j = 0; j < 4; ++j)
#pragma unroll
      for (int r = 0; r < 4; ++r) {
        float p = __expf(S[j][r] - mrow);  // bounded by e^8
        S[j][r] = p;
        rs += p;
      }
    lpart += rs;  // per-lane partial (this quad's kv slice); reduced at end
    __syncthreads();  // B: K frags consumed; Ks reusable as P
#pragma unroll
    for (int j = 0; j < 4; ++j) {
      alignas(8) bf16 tmp[4];
#pragma unroll
      for (int r = 0; r < 4; ++r) tmp[r] = __float2bfloat16(S[j][r]);
      *(uint64_t*)(rowP + j * 16 + quad * 4) = *(const uint64_t*)tmp;
    }
    __threadfence_block();
    __builtin_amdgcn_wave_barrier();
    bf16x8 pf0 = *(const bf16x8*)(rowP + quad * 8);
    bf16x8 pf1 = *(const bf16x8*)(rowP + 32 + quad * 8);
#pragma unroll
    for (int jj = 0; jj < 4; ++jj) {
      bf16x8 vf0 = read_frag_swz(Vs, jj * 16 + c, quad);
      bf16x8 vf1 = read_frag_swz(Vs, jj * 16 + c, quad + 4);
      o[jj] = mfma16(pf0, vf0, o[jj]);
      o[jj] = mfma16(pf1, vf1, o[jj]);
    }
    __syncthreads();  // C: P/V consumed; safe to restage
  }

  // one-time l reduction: per-lane quad partials -> row totals
  float lsum = lpart + __shfl_xor(lpart, 16, 64);
  lsum += __shfl_xor(lsum, 32, 64);
  float lr4[4];
#pragma unroll
  for (int r = 0; r < 4; ++r) lr4[r] = __shfl(lsum, quad * 4 + r, 64);
#pragma unroll
  for (int jj = 0; jj < 4; ++jj)
#pragma unroll
    for (int r = 0; r < 4; ++r) {
      int qi = qb + quad * 4 + r;
      out[(((size_t)b * 1024 + qi) * 16 + h) * 64 + jj * 16 + c] =
          __float2bfloat16(o[jj][r] / lr4[r]);
    }
}

// ---------------------------------------------------------------------------
// Memory plan (unchanged, proven):
//   d_out (32 MB fp32): [0,16M) q bf16 | [16M,32M) x_bf16.
//   ws: k 4MB @0 | vT 4MB @4M | attn 16MB @8M
//   Wq/Wk/Wv_bf @8M/10M/10.5M (attn region, dead before attn_kernel writes).
//   Wo_bf @0 (k region; converted AFTER attn_kernel consumed k).
// ---------------------------------------------------------------------------
extern "C" void kernel_launch(void* const* d_in, const int* in_sizes, int n_in,
                              void* d_out, int out_size, void* d_ws,
                              size_t ws_size, hipStream_t stream) {
  const float* x = (const float*)d_in[0];
  const float* Wq = (const float*)d_in[1];
  const float* Wk = (const float*)d_in[2];
  const float* Wv = (const float*)d_in[3];
  const float* Wo = (const float*)d_in[4];
  const float* E = (const float*)d_in[5];

  char* ws = (char*)d_ws;
  bf16* q_ws = (bf16*)d_out;                           // [0,16M) of d_out
  bf16* x_bf = (bf16*)((char*)d_out + (16ull << 20));  // [16M,32M) of d_out
  bf16* k_ws = (bf16*)(ws);
  bf16* vT = (bf16*)(ws + (4ull << 20));
  bf16* attn = (bf16*)(ws + (8ull << 20));
  bf16* Wq_bf = (bf16*)(ws + (8ull << 20));            // 2 MB   (attn region)
  bf16* Wk_bf = (bf16*)(ws + (10ull << 20));           // 0.5 MB (attn region)
  bf16* Wv_bf = (bf16*)(ws + (10ull << 20) + (512ull << 10));  // 0.5 MB
  bf16* Wo_bf = (bf16*)(ws);                           // 2 MB   (k region)
  float* outp = (float*)d_out;

  cvt_bf16<<<2048, 256, 0, stream>>>(x, x_bf, 2097152);
  cvt_bf16<<<1024, 256, 0, stream>>>(Wq, Wq_bf, 262144);
  cvt_bf16<<<256, 256, 0, stream>>>(Wk, Wk_bf, 65536);
  cvt_bf16<<<256, 256, 0, stream>>>(Wv, Wv_bf, 65536);
  gemm_qkv<<<dim3(12, 64), 256, 0, stream>>>(x_bf, Wq_bf, Wk_bf, Wv_bf,
                                             q_ws, k_ws, vT);
  attn_kernel<<<dim3(16, 128), 256, 0, stream>>>(q_ws, k_ws, vT, E, attn);
  cvt_bf16<<<1024, 256, 0, stream>>>(Wo, Wo_bf, 262144);
  gemm_o<<<dim3(8, 64), 256, 0, stream>>>(attn, Wo_bf, outp);
}